// Round 3
// baseline (1161.167 us; speedup 1.0000x reference)
//
#include <hip/hip_runtime.h>
#include <stdint.h>
#include <stddef.h>

// ---------------------------------------------------------------------------
// InverseImportanceLinear: out = x @ W_deq^T + bias
//   W_deq[k,n] = (Q[k,n] - zeros[k,n/64]) * scales[k,n/64] * mu2[k] * mu1[n]
// R3: dequant FUSED into GEMM B-staging (no W materialization round-trip).
//   x' = x*mu1 -> bf16 (ws).  GEMM: A staged via global_load_lds (swizzled),
//   B staged via regs: load Q i32x4, dequant to bf16, ds_write_b128 into the
//   same XOR-swizzled LDS layout (conflicts measured 0 in R2). Q prefetched
//   across the MFMA section. bias fused in epilogue. fp32 out.
// ---------------------------------------------------------------------------

typedef __attribute__((ext_vector_type(8))) short bfrag;   // 8 bf16 = 4 VGPRs
typedef __attribute__((ext_vector_type(4))) float f32x4;
typedef __attribute__((ext_vector_type(4))) int   i32x4;

__device__ __forceinline__ short f2bf(float f) {          // RNE (for x')
    uint32_t u = __float_as_uint(f);
    u += 0x7fffu + ((u >> 16) & 1u);
    return (short)(u >> 16);
}

__device__ __forceinline__ short f2bfr(float f) {         // round-half-up, 2 ops
    uint32_t u = __float_as_uint(f);
    return (short)((u + 0x8000u) >> 16);
}

__device__ __forceinline__ void gload_lds16(const void* g, void* l) {
    __builtin_amdgcn_global_load_lds(
        (const __attribute__((address_space(1))) void*)g,
        (__attribute__((address_space(3))) void*)l,
        16, 0, 0);
}

// ---- phase 1: x fp32 * mu1 -> bf16 --------------------------------------
__global__ void cvt_x_kernel(const float* __restrict__ x,
                             const float* __restrict__ mu1,
                             short* __restrict__ xb, int per /* N/8 */) {
    int i = blockIdx.x * 256 + threadIdx.x;          // 8-element chunk index
    int cb = (i % per) * 8;                          // column base (n)
    const f32x4* xv = (const f32x4*)x;
    f32x4 a = xv[2 * i];
    f32x4 b = xv[2 * i + 1];
    const f32x4* uv = (const f32x4*)(mu1 + cb);
    f32x4 u0 = uv[0];
    f32x4 u1 = uv[1];
    bfrag o;
    o[0] = f2bf(a[0] * u0[0]); o[1] = f2bf(a[1] * u0[1]);
    o[2] = f2bf(a[2] * u0[2]); o[3] = f2bf(a[3] * u0[3]);
    o[4] = f2bf(b[0] * u1[0]); o[5] = f2bf(b[1] * u1[1]);
    o[6] = f2bf(b[2] * u1[2]); o[7] = f2bf(b[3] * u1[3]);
    ((bfrag*)xb)[i] = o;
}

// ---- phase 2: fused dequant + bf16 GEMM, C = A @ W_deq^T + bias ---------
// LDS invariant (both operands): 16B chunk (row m, kchunk kc) stored at
// chunk position m*4 + (kc ^ ((m>>1)&3)).
#define BM 128
#define BN 128
#define BK 32

__global__ void gemm_fused_kernel(const short* __restrict__ A,   // T x Kc bf16
                                  const int* __restrict__ Q,     // K x Kc i32
                                  const float* __restrict__ scales,
                                  const float* __restrict__ zeros,
                                  const float* __restrict__ mu2,
                                  const float* __restrict__ bias,
                                  float* __restrict__ C,
                                  int Kc, int Nout, int NG) {
    __shared__ __attribute__((aligned(16))) short As[BM * BK];
    __shared__ __attribute__((aligned(16))) short Bs[BN * BK];

    const int tid  = threadIdx.x;
    const int lane = tid & 63;
    const int wave = tid >> 6;
    const int wm   = (wave >> 1) * 64;     // wave's 64-row quadrant (M)
    const int wn   = (wave & 1) * 64;      // wave's 64-col quadrant (N=K-out)
    const int bm   = blockIdx.y * BM;      // output row base
    const int bn   = blockIdx.x * BN;      // output col base (W row base)

    f32x4 acc[4][4];
#pragma unroll
    for (int i = 0; i < 4; i++)
#pragma unroll
        for (int j = 0; j < 4; j++)
            acc[i][j] = (f32x4){0.f, 0.f, 0.f, 0.f};

    // --- A staging (async, global chunk permuted to realize LDS swizzle) ---
    const int skc = ((tid & 3) ^ ((tid >> 3) & 3)) * 8;
    const short* gA  = A + (size_t)(bm + (tid >> 2)) * Kc + skc;
    const short* gA2 = gA + (size_t)64 * Kc;
    short* lA  = As + tid * 8;
    short* lA2 = As + 2048 + tid * 8;

    // --- B fused staging: thread -> (row = tid>>1, 16-col half = tid&1) ---
    const int brow = tid >> 1;             // 0..127
    const int bkh  = tid & 1;
    const int krow = bn + brow;            // global W row
    const int* gq = Q + (size_t)krow * Kc + bkh * 16;
    const float* sp = scales + (size_t)krow * NG;
    const float* zp = zeros  + (size_t)krow * NG;
    const float m2 = mu2[krow];
    const int sw_b = (brow >> 1) & 3;
    const int kc0  = 2 * bkh;
    short* lB0 = Bs + ((size_t)brow * 4 + (kc0 ^ sw_b)) * 8;
    short* lB1 = Bs + ((size_t)brow * 4 + ((kc0 + 1) ^ sw_b)) * 8;

    // prologue: load first Q block + s/z (group 0)
    i32x4 q0, q1, q2, q3;
    {
        const i32x4* qv = (const i32x4*)gq;
        q0 = qv[0]; q1 = qv[1]; q2 = qv[2]; q3 = qv[3];
    }
    float s = sp[0] * m2;
    float z = zp[0];

    // --- fragment read addressing (XOR-swizzled, conflicts = 0) ---
    const int r  = lane & 15;
    const int kc = lane >> 4;
    const int sw = (kc ^ ((r >> 1) & 3)) * 8;
    const short* pa = As + (wm + r) * BK + sw;
    const short* pb = Bs + (wn + r) * BK + sw;

    for (int k0 = 0; k0 < Kc; k0 += BK) {
        // async A tile
        gload_lds16(gA + k0, lA);
        gload_lds16(gA2 + k0, lA2);

        // prefetch next Q block + group constants (uniform branch)
        i32x4 qn0 = q0, qn1 = q1, qn2 = q2, qn3 = q3;
        float sn = s, zn = z;
        int k1 = k0 + BK;
        if (k1 < Kc) {
            const i32x4* qv = (const i32x4*)(gq + k1);
            qn0 = qv[0]; qn1 = qv[1]; qn2 = qv[2]; qn3 = qv[3];
            if ((k1 & 63) == 0) {
                sn = sp[k1 >> 6] * m2;
                zn = zp[k1 >> 6];
            }
        }

        // dequant current 16 ints -> 2 bf16 chunks, write to swizzled LDS
        bfrag o0, o1;
        o0[0] = f2bfr(((float)q0[0] - z) * s);
        o0[1] = f2bfr(((float)q0[1] - z) * s);
        o0[2] = f2bfr(((float)q0[2] - z) * s);
        o0[3] = f2bfr(((float)q0[3] - z) * s);
        o0[4] = f2bfr(((float)q1[0] - z) * s);
        o0[5] = f2bfr(((float)q1[1] - z) * s);
        o0[6] = f2bfr(((float)q1[2] - z) * s);
        o0[7] = f2bfr(((float)q1[3] - z) * s);
        o1[0] = f2bfr(((float)q2[0] - z) * s);
        o1[1] = f2bfr(((float)q2[1] - z) * s);
        o1[2] = f2bfr(((float)q2[2] - z) * s);
        o1[3] = f2bfr(((float)q2[3] - z) * s);
        o1[4] = f2bfr(((float)q3[0] - z) * s);
        o1[5] = f2bfr(((float)q3[1] - z) * s);
        o1[6] = f2bfr(((float)q3[2] - z) * s);
        o1[7] = f2bfr(((float)q3[3] - z) * s);
        *(bfrag*)lB0 = o0;
        *(bfrag*)lB1 = o1;

        __syncthreads();                   // drains vmcnt(A) + lgkm(B writes)

        bfrag af[4], bfv[4];
#pragma unroll
        for (int i = 0; i < 4; i++) af[i]  = *(const bfrag*)(pa + i * 16 * BK);
#pragma unroll
        for (int j = 0; j < 4; j++) bfv[j] = *(const bfrag*)(pb + j * 16 * BK);

#pragma unroll
        for (int i = 0; i < 4; i++)
#pragma unroll
            for (int j = 0; j < 4; j++)
                acc[i][j] = __builtin_amdgcn_mfma_f32_16x16x32_bf16(
                    af[i], bfv[j], acc[i][j], 0, 0, 0);

        __syncthreads();                   // reads done before next overwrite

        q0 = qn0; q1 = qn1; q2 = qn2; q3 = qn3;
        s = sn; z = zn;
    }

    // epilogue: C/D layout col = lane&15, row = (lane>>4)*4 + reg
    const int row0  = bm + wm + (lane >> 4) * 4;
    const int colg0 = bn + wn;
#pragma unroll
    for (int j = 0; j < 4; j++) {
        int col  = colg0 + j * 16 + r;
        float bv = bias[col];
#pragma unroll
        for (int i = 0; i < 4; i++) {
            int row = row0 + i * 16;
#pragma unroll
            for (int q = 0; q < 4; q++)
                C[(size_t)(row + q) * Nout + col] = acc[i][j][q] + bv;
        }
    }
}

// ---- emergency fallback (workspace too small) ---------------------------
__global__ void naive_kernel(const float* __restrict__ x, const int* __restrict__ Q,
                             const float* __restrict__ scales, const float* __restrict__ zeros,
                             const float* __restrict__ mu1, const float* __restrict__ mu2,
                             const float* __restrict__ bias, float* __restrict__ out,
                             int T, int N, int K, int NG) {
    long long total = (long long)T * K;
    for (long long idx = blockIdx.x * 256ll + threadIdx.x; idx < total;
         idx += (long long)gridDim.x * 256ll) {
        int t = (int)(idx / K);
        int k = (int)(idx - (long long)t * K);
        float s = 0.f;
        for (int n = 0; n < N; n++) {
            int g = n >> 6;
            float w = ((float)Q[(size_t)k * N + n] - zeros[(size_t)k * NG + g]) *
                      scales[(size_t)k * NG + g];
            s += x[(size_t)t * N + n] * w * mu1[n];
        }
        out[idx] = s * mu2[k] + bias[k];
    }
}

extern "C" void kernel_launch(void* const* d_in, const int* in_sizes, int n_in,
                              void* d_out, int out_size, void* d_ws, size_t ws_size,
                              hipStream_t stream) {
    const float* x      = (const float*)d_in[0];
    const int*   Q      = (const int*)d_in[1];
    const float* scales = (const float*)d_in[2];
    const float* zeros  = (const float*)d_in[3];
    const float* mu1    = (const float*)d_in[4];
    const float* mu2    = (const float*)d_in[5];
    const float* bias   = (const float*)d_in[6];
    float* out = (float*)d_out;

    const int N  = in_sizes[4];            // 4096 (contraction)
    const int K  = in_sizes[5];            // 11264 (output cols)
    const int T  = in_sizes[0] / N;        // 4096 (output rows)
    const int NG = in_sizes[2] / K;        // 64 groups

    const size_t xb_bytes = (size_t)T * N * 2;       // x' in bf16

    if (ws_size < xb_bytes) {
        naive_kernel<<<4096, 256, 0, stream>>>(x, Q, scales, zeros, mu1, mu2,
                                               bias, out, T, N, K, NG);
        return;
    }

    short* xb = (short*)d_ws;
    cvt_x_kernel<<<(T * N / 8) / 256, 256, 0, stream>>>(x, mu1, xb, N / 8);

    dim3 ggrid(K / BN, T / BM);
    gemm_fused_kernel<<<ggrid, 256, 0, stream>>>(xb, Q, scales, zeros, mu2,
                                                 bias, out, N, K, NG);
}